// Round 5
// baseline (13574.709 us; speedup 1.0000x reference)
//
#include <hip/hip_runtime.h>
#include <hip/hip_bf16.h>
#include <math.h>

typedef __hip_bfloat16 bf16;

constexpr int NB  = 2048;
constexpr int NJ  = 7;
constexpr int ND  = 128;
constexpr int NHD = 8;
constexpr int NLYR= 4;
constexpr int NFF = 512;
constexpr int NTR = 35;
constexpr int NAS = 70;

struct KArgs { const void* p[54]; void* out; const void* flag; };

__device__ __forceinline__ float ldv(const float* p, size_t i){ return p[i]; }
__device__ __forceinline__ float ldv(const bf16* p, size_t i){ return __bfloat162float(p[i]); }
__device__ __forceinline__ void stv(float* p, size_t i, float v){ p[i]=v; }
__device__ __forceinline__ void stv(bf16* p, size_t i, float v){ p[i]=__float2bfloat16(v); }
__device__ __forceinline__ float gelu_f(float x){
  return 0.5f*x*(1.0f+erff(x*0.70710678118654752f));
}
__device__ __forceinline__ bool bad_f32(float v){
  unsigned int u=__float_as_uint(v);
  return (u&0x7F800000u)==0x7F800000u;
}

__device__ void build_trips(int* tr){
  int n=0;
  for(int a=0;a<NJ;a++)for(int b=a+1;b<NJ;b++)for(int c=b+1;c<NJ;c++){
    tr[n*3+0]=a; tr[n*3+1]=b; tr[n*3+2]=c; n++;
  }
}
__device__ int find_tid(const int* tr,int a,int b,int c){
  for(int t=0;t<NTR;t++) if(tr[t*3]==a&&tr[t*3+1]==b&&tr[t*3+2]==c) return t;
  return 0;
}
__device__ void build_assign(const int* tr,int* isr,int* g1t,int* g2t,int* g1j,int* g2j){
  int n=0;
  for(int is=0;is<NJ;is++){
    int rem[6],m=0;
    for(int j=0;j<NJ;j++) if(j!=is) rem[m++]=j;
    for(int i=0;i<6;i++)for(int jj=i+1;jj<6;jj++)for(int k=jj+1;k<6;k++){
      int c0=rem[i],c1=rem[jj],c2=rem[k];
      int comp[3],q=0;
      for(int r=0;r<6;r++){ int v=rem[r]; if(v!=c0&&v!=c1&&v!=c2) comp[q++]=v; }
      bool lt=(c0<comp[0])||(c0==comp[0]&&(c1<comp[1]||(c1==comp[1]&&c2<comp[2])));
      if(lt){
        isr[n]=is;
        g1j[n*3]=c0; g1j[n*3+1]=c1; g1j[n*3+2]=c2;
        g2j[n*3]=comp[0]; g2j[n*3+1]=comp[1]; g2j[n*3+2]=comp[2];
        g1t[n]=find_tid(tr,c0,c1,c2);
        g2t[n]=find_tid(tr,comp[0],comp[1],comp[2]);
        n++;
      }
    }
  }
}

template<typename T>
__device__ void mmr(const float* a, const T* W, const T* bias, float* out,
                    int M, int K, int N, int tid, int act, bool accum){
  for(int idx=tid; idx<M*N; idx+=256){
    int i=idx/N, k=idx-i*N;
    float acc = bias ? ldv(bias,k) : 0.0f;
    const float* ar=a+i*K;
    for(int d=0; d<K; d++) acc += ar[d]*ldv(W,(size_t)d*N+k);
    if(act==1) acc=fmaxf(acc,0.0f);
    else if(act==2) acc=gelu_f(acc);
    if(accum) out[idx]+=acc; else out[idx]=acc;
  }
  __syncthreads();
}

template<typename T>
__device__ void lnr(const float* src, float* dst, const T* g, const T* bb,
                    float* mu, float* rs, int rows, int tid){
  if(tid<rows){
    const float* r=src+tid*ND;
    float m=0.f;
    for(int d=0;d<ND;d++) m+=r[d];
    m*=(1.0f/ND);
    float v=0.f;
    for(int d=0;d<ND;d++){ float t=r[d]-m; v+=t*t; }
    v*=(1.0f/ND);
    mu[tid]=m; rs[tid]=rsqrtf(v+1e-5f);
  }
  __syncthreads();
  for(int idx=tid; idx<rows*ND; idx+=256){
    int j=idx>>7, d=idx&127;
    dst[idx]=(src[idx]-mu[j])*rs[j]*ldv(g,d)+ldv(bb,d);
  }
  __syncthreads();
}

// block-parallel NaN/Inf scan of an LDS buffer; ORs bit into *badS
__device__ void scanbuf(const float* s, int n, unsigned bit, unsigned* badS,
                        int tid, int* tmp){
  int my=0;
  for(int i=tid;i<n;i+=256) if(bad_f32(s[i])) my=1;
  tmp[tid]=my;
  __syncthreads();
  if(tid==0){ int any=0; for(int i=0;i<256;i++) any|=tmp[i]; if(any) *badS|=bit; }
  __syncthreads();
}

__global__ void k_detect(const unsigned short* w, int n, unsigned* flag){
  __shared__ int bad[256];
  int tid=threadIdx.x;
  int my=0;
  for(int i=tid;i<n;i+=256){
    unsigned e=(w[i]>>7)&0xFFu;   // bf16 exponent field
    if(e>=134u) my=1;             // |v|>=128 or inf/nan: impossible for real bf16 weights
  }
  bad[tid]=my;
  __syncthreads();
  if(tid==0){
    int any=0; for(int i=0;i<256;i++) any|=bad[i];
    flag[0]= any?1u:0u;           // 1 => inputs are fp32; 0 => bf16
  }
}

template<typename T>
__global__ __launch_bounds__(256) void k_all(KArgs A, unsigned want){
  if(((const unsigned*)A.flag)[0]!=want) return;   // uniform exit for wrong-dtype instance
  const T* fm   =(const T*)A.p[0];  const T* Win  =(const T*)A.p[1];  const T* bin  =(const T*)A.p[2];
  const T* ptw  =(const T*)A.p[3];  const T* drw  =(const T*)A.p[4];  const T* mw   =(const T*)A.p[5];
  const T* eWqkv=(const T*)A.p[6];  const T* ebqkv=(const T*)A.p[7];  const T* eWo  =(const T*)A.p[8];
  const T* ebo  =(const T*)A.p[9];  const T* eg1  =(const T*)A.p[10]; const T* eb1  =(const T*)A.p[11];
  const T* eg2  =(const T*)A.p[12]; const T* eb2  =(const T*)A.p[13]; const T* eW1  =(const T*)A.p[14];
  const T* ebb1 =(const T*)A.p[15]; const T* eW2  =(const T*)A.p[16]; const T* ebb2 =(const T*)A.p[17];
  const T* tWq  =(const T*)A.p[18]; const T* tbq  =(const T*)A.p[19]; const T* tWk  =(const T*)A.p[20];
  const T* tbk  =(const T*)A.p[21]; const T* tWv  =(const T*)A.p[22]; const T* tbv  =(const T*)A.p[23];
  const T* tWo  =(const T*)A.p[24]; const T* tbo  =(const T*)A.p[25]; const T* tg1  =(const T*)A.p[26];
  const T* tb1  =(const T*)A.p[27]; const T* tW1  =(const T*)A.p[28]; const T* tbb1 =(const T*)A.p[29];
  const T* tW2  =(const T*)A.p[30]; const T* tbb2 =(const T*)A.p[31]; const T* tg2  =(const T*)A.p[32];
  const T* tb2  =(const T*)A.p[33]; const T* gWqkv=(const T*)A.p[34]; const T* gbqkv=(const T*)A.p[35];
  const T* gWo  =(const T*)A.p[36]; const T* gbo  =(const T*)A.p[37]; const T* gg1  =(const T*)A.p[38];
  const T* gb1  =(const T*)A.p[39]; const T* gg2  =(const T*)A.p[40]; const T* gb2  =(const T*)A.p[41];
  const T* gW1  =(const T*)A.p[42]; const T* gbb1 =(const T*)A.p[43]; const T* gW2  =(const T*)A.p[44];
  const T* gbb2 =(const T*)A.p[45]; const T* phg  =(const T*)A.p[46]; const T* phb  =(const T*)A.p[47];
  const T* sW1  =(const T*)A.p[48]; const T* sb1  =(const T*)A.p[49]; const T* sW2  =(const T*)A.p[50];
  const T* sb2  =(const T*)A.p[51]; const T* sW3  =(const T*)A.p[52]; const T* sb3  =(const T*)A.p[53];
  T* OUT=(T*)A.out;

  int b=blockIdx.x, tid=threadIdx.x;

  __shared__ float xS[NJ*ND];
  __shared__ float biasS[NHD*NJ*NJ];
  __shared__ float evtS[ND];
  __shared__ float fmvS[NJ*4];
  __shared__ float grpS[NTR*ND];
  __shared__ float muS[16], rsS[16];
  __shared__ float P[7400];
  __shared__ int trS[NTR*3];
  __shared__ int isrS[NAS], g1tS[NAS], g2tS[NAS], g1jS[NAS*3], g2jS[NAS*3];
  __shared__ int tmpS[256];
  __shared__ unsigned badS;

  if(tid==0){ build_trips(trS); build_assign(trS,isrS,g1tS,g2tS,g1jS,g2jS); badS=0u; }
  __syncthreads();

  // ================= phase 0: embed + pairwise bias =================
  {
    float* fE =P+6000; float* fpx=P+6008; float* fpy=P+6016; float* fpz=P+6024;
    float* flp=P+6032; float* fet=P+6040; float* fcp=P+6048; float* fsp=P+6056;
    float* fph=P+6064; float* fms=P+6072;
    if(tid<NJ){
      size_t base=((size_t)b*NJ+tid)*4;
      float e=ldv(fm,base+0), x_=ldv(fm,base+1), y_=ldv(fm,base+2), z_=ldv(fm,base+3);
      float pt=fmaxf(sqrtf(x_*x_+y_*y_),1e-8f);
      fE[tid]=e; fpx[tid]=x_; fpy[tid]=y_; fpz[tid]=z_;
      flp[tid]=logf(pt);
      fet[tid]=asinhf(z_/pt);
      fph[tid]=atan2f(y_,x_);
      fms[tid]=sqrtf(fmaxf(e*e-x_*x_-y_*y_-z_*z_,1e-8f));
      fcp[tid]=x_/pt; fsp[tid]=y_/pt;
    }
    if(tid>=32&&tid<32+NJ*4){ int q=tid-32; fmvS[q]=ldv(fm,(size_t)b*NJ*4+q); }
    __syncthreads();
    for(int idx=tid; idx<NJ*ND; idx+=256){
      int j=idx>>7, d=idx&127;
      float in8[8]={fE[j],fpx[j],fpy[j],fpz[j],flp[j],fet[j],fph[j],fms[j]};
      float acc=ldv(bin,d);
      for(int c=0;c<8;c++) acc += in8[c]*ldv(Win,c*ND+d);
      xS[idx]=acc;
    }
    for(int idx=tid; idx<NHD*NJ*NJ; idx+=256){
      int h=idx/49, r=idx%49, i=r/7, jj=r%7;
      float ptb=flp[i]-flp[jj];
      float deta=fet[i]-fet[jj];
      float cd=fcp[i]*fcp[jj]+fsp[i]*fsp[jj];
      cd=fminf(fmaxf(cd,-1.0f+1e-7f),1.0f-1e-7f);
      float ac=acosf(cd);
      float dr=sqrtf(deta*deta+ac*ac);
      float Es=fE[i]+fE[jj];
      float sx=fpx[i]+fpx[jj], sy=fpy[i]+fpy[jj], sz=fpz[i]+fpz[jj];
      float mb=0.5f*logf(fmaxf(Es*Es-(sx*sx+sy*sy+sz*sz),1e-8f));
      biasS[idx]=ldv(ptw,h)*ptb+ldv(drw,h)*dr+ldv(mw,h)*mb;
    }
    __syncthreads();
    scanbuf(xS,NJ*ND,1u,&badS,tid,tmpS);
    scanbuf(biasS,NHD*NJ*NJ,1u,&badS,tid,tmpS);
  }

  // ================= phase 1: 4 encoder layers =================
  {
    float* h  =P+0;
    float* qkv=P+896;
    float* att=P+3584;
    float* sb =P+4480;
    float* ff =P+896;
    for(int l=0;l<NLYR;l++){
      lnr(xS,h,eg1+l*ND,eb1+l*ND,muS,rsS,NJ,tid);
      mmr(h,eWqkv+(size_t)l*ND*3*ND,ebqkv+l*3*ND,qkv,NJ,ND,3*ND,tid,0,false);
      for(int idx=tid;idx<NHD*NJ*NJ;idx+=256){
        int hh=idx/49, r=idx%49, i=r/7, jj=r%7;
        float acc=0.f;
        const float* qr=&qkv[i*384+hh*16];
        const float* kr=&qkv[jj*384+128+hh*16];
        for(int d=0;d<16;d++) acc+=qr[d]*kr[d];
        sb[idx]=acc*0.25f+biasS[idx];
      }
      __syncthreads();
      if(tid<NHD*NJ){
        float* s=&sb[tid*7];
        float mx=s[0]; for(int j=1;j<7;j++) mx=fmaxf(mx,s[j]);
        float sm=0.f; for(int j=0;j<7;j++){ s[j]=expf(s[j]-mx); sm+=s[j]; }
        float inv=1.0f/sm; for(int j=0;j<7;j++) s[j]*=inv;
      }
      __syncthreads();
      for(int idx=tid;idx<NJ*ND;idx+=256){
        int i=idx>>7, d=idx&127, hh=d>>4;
        float acc=0.f;
        for(int j=0;j<7;j++) acc+=sb[(hh*7+i)*7+j]*qkv[j*384+256+d];
        att[idx]=acc;
      }
      __syncthreads();
      mmr(att,eWo+(size_t)l*ND*ND,ebo+l*ND,xS,NJ,ND,ND,tid,0,true);
      lnr(xS,h,eg2+l*ND,eb2+l*ND,muS,rsS,NJ,tid);
      mmr(h,eW1+(size_t)l*ND*NFF,ebb1+l*NFF,ff,NJ,ND,NFF,tid,1,false);
      mmr(ff,eW2+(size_t)l*NFF*ND,ebb2+l*ND,xS,NJ,NFF,ND,tid,0,true);
    }
    scanbuf(xS,NJ*ND,2u,&badS,tid,tmpS);
  }

  // ================= phase 2: triplet cross-attention =================
  {
    float* q   =P+0;
    float* kv  =P+896;
    float* sb4 =P+5376;
    float* att2=P+6356;
    float* tff =P+0;
    const float sc=0.17677669529663687f;
    mmr(xS,tWq,tbq,q,NJ,ND,ND,tid,0,false);
    for(int idx=tid;idx<NTR*ND;idx+=256){
      int t=idx>>7, d=idx&127;
      int a0=trS[t*3]*ND, a1=trS[t*3+1]*ND, a2=trS[t*3+2]*ND;
      float acc=ldv(tbk,d);
      for(int c=0;c<ND;c++){
        float tv=(xS[a0+c]+xS[a1+c]+xS[a2+c])*(1.0f/3.0f);
        acc+=tv*ldv(tWk,(size_t)c*ND+d);
      }
      kv[idx]=acc;
    }
    __syncthreads();
    for(int idx=tid;idx<4*NJ*NTR;idx+=256){
      int hh=idx/245, r=idx%245, i=r/35, t=r%35;
      float acc=0.f;
      const float* qr=&q[i*ND+hh*32];
      const float* kr=&kv[t*ND+hh*32];
      for(int d=0;d<32;d++) acc+=qr[d]*kr[d];
      bool mem=(trS[t*3]==i||trS[t*3+1]==i||trS[t*3+2]==i);
      sb4[idx]=acc*sc+(mem?0.0f:-1e9f);
    }
    __syncthreads();
    if(tid<4*NJ){
      float* s=&sb4[tid*35];
      float mx=-3e38f; for(int t=0;t<35;t++) mx=fmaxf(mx,s[t]);
      float sm=0.f; for(int t=0;t<35;t++){ s[t]=expf(s[t]-mx); sm+=s[t]; }
      float inv=1.0f/sm; for(int t=0;t<35;t++) s[t]*=inv;
    }
    __syncthreads();
    for(int idx=tid;idx<NTR*ND;idx+=256){
      int t=idx>>7, d=idx&127;
      int a0=trS[t*3]*ND, a1=trS[t*3+1]*ND, a2=trS[t*3+2]*ND;
      float acc=ldv(tbv,d);
      for(int c=0;c<ND;c++){
        float tv=(xS[a0+c]+xS[a1+c]+xS[a2+c])*(1.0f/3.0f);
        acc+=tv*ldv(tWv,(size_t)c*ND+d);
      }
      kv[idx]=acc;
    }
    __syncthreads();
    for(int idx=tid;idx<NJ*ND;idx+=256){
      int i=idx>>7, d=idx&127, hh=d>>5;
      float acc=0.f;
      for(int t=0;t<35;t++) acc+=sb4[(hh*7+i)*35+t]*kv[t*ND+d];
      att2[idx]=acc;
    }
    __syncthreads();
    mmr(att2,tWo,tbo,xS,NJ,ND,ND,tid,0,true);
    lnr(xS,xS,tg1,tb1,muS,rsS,NJ,tid);
    mmr(xS,tW1,tbb1,tff,NJ,ND,2*ND,tid,2,false);
    mmr(tff,tW2,tbb2,xS,NJ,2*ND,ND,tid,0,true);
    lnr(xS,xS,tg2,tb2,muS,rsS,NJ,tid);
    if(tid<ND){
      float s=0.f; for(int j=0;j<NJ;j++) s+=xS[j*ND+tid];
      evtS[tid]=s*(1.0f/NJ);
    }
    __syncthreads();
    scanbuf(xS,NJ*ND,4u,&badS,tid,tmpS);
  }

  // ================= phase 3: group transformer (chunks of 3 triplets) =================
  {
    float* xg  =P+0;
    float* hg  =P+1152;
    float* qkvg=P+2304;
    float* attg=P+5760;
    float* sbg =P+6912;
    float* ffg =P+2304;
    const float sc=0.17677669529663687f;
    for(int c0=0;c0<NTR;c0+=3){
      int tc=(NTR-c0)<3?(NTR-c0):3;
      int ntok=3*tc;
      for(int idx=tid;idx<ntok*ND;idx+=256){
        int s=idx>>7, d=idx&127; int t=c0+s/3, r=s%3;
        xg[idx]=xS[trS[t*3+r]*ND+d];
      }
      __syncthreads();
      lnr(xg,hg,gg1,gb1,muS,rsS,ntok,tid);
      mmr(hg,gWqkv,gbqkv,qkvg,ntok,ND,3*ND,tid,0,false);
      for(int idx=tid;idx<tc*36;idx+=256){
        int s=idx/36, r=idx%36, hh=r/9, p=r%9, i=p/3, j=p%3;
        float acc=0.f;
        const float* qr=&qkvg[(s*3+i)*384+hh*32];
        const float* kr=&qkvg[(s*3+j)*384+128+hh*32];
        for(int d=0;d<32;d++) acc+=qr[d]*kr[d];
        sbg[idx]=acc*sc;
      }
      __syncthreads();
      for(int q2=tid;q2<tc*12;q2+=256){
        int s=q2/12, r2=q2%12;
        float* base=&sbg[s*36+(r2/3)*9+(r2%3)*3];
        float mx=fmaxf(base[0],fmaxf(base[1],base[2]));
        float e0=expf(base[0]-mx),e1=expf(base[1]-mx),e2=expf(base[2]-mx);
        float inv=1.0f/(e0+e1+e2);
        base[0]=e0*inv; base[1]=e1*inv; base[2]=e2*inv;
      }
      __syncthreads();
      for(int idx=tid;idx<ntok*ND;idx+=256){
        int sr=idx>>7, d=idx&127; int s=sr/3, i=sr%3, hh=d>>5;
        float acc=0.f;
        for(int j=0;j<3;j++) acc+=sbg[s*36+hh*9+i*3+j]*qkvg[(s*3+j)*384+256+d];
        attg[idx]=acc;
      }
      __syncthreads();
      mmr(attg,gWo,gbo,xg,ntok,ND,ND,tid,0,true);
      lnr(xg,hg,gg2,gb2,muS,rsS,ntok,tid);
      mmr(hg,gW1,gbb1,ffg,ntok,ND,2*ND,tid,1,false);
      mmr(ffg,gW2,gbb2,xg,ntok,2*ND,ND,tid,0,true);
      for(int idx=tid;idx<tc*ND;idx+=256){
        int s=idx>>7, d=idx&127;
        grpS[(c0+s)*ND+d]=(xg[(s*3)*ND+d]+xg[(s*3+1)*ND+d]+xg[(s*3+2)*ND+d])*(1.0f/3.0f);
      }
      __syncthreads();
    }
    scanbuf(grpS,NTR*ND,8u,&badS,tid,tmpS);
  }

  // ================= phase 4: assignment scorer =================
  {
    float* isr_c=P+0;
    float* h1   =P+1792;
    float* h2   =P+2048;
    float* phys =P+2176;
    float* evt_c=P+2208;
    {
      int k=tid;
      float acc=ldv(sb1,k);
      for(int d=0;d<ND;d++) acc+=evtS[d]*ldv(sW1,(size_t)(4*ND+d)*2*ND+k);
      evt_c[k]=acc;
    }
    for(int idx=tid;idx<NJ*2*ND;idx+=256){
      int j=idx/(2*ND), k=idx%(2*ND);
      float acc=0.f;
      for(int d=0;d<ND;d++) acc+=xS[j*ND+d]*ldv(sW1,(size_t)d*2*ND+k);
      isr_c[j*2*ND+k]=acc;
    }
    __syncthreads();
    for(int a=0;a<NAS;a++){
      if(tid==0){
        for(int g=0;g<4;g++){
          float p[4];
          for(int c=0;c<4;c++){
            float v;
            if(g==0)      v=fmvS[g1jS[a*3]*4+c]+fmvS[g1jS[a*3+1]*4+c]+fmvS[g1jS[a*3+2]*4+c];
            else if(g==1) v=fmvS[g2jS[a*3]*4+c]+fmvS[g2jS[a*3+1]*4+c]+fmvS[g2jS[a*3+2]*4+c];
            else if(g==2) v=fmvS[isrS[a]*4+c];
            else          v=fmvS[g1jS[a*3]*4+c]+fmvS[g1jS[a*3+1]*4+c]+fmvS[g1jS[a*3+2]*4+c]
                           +fmvS[g2jS[a*3]*4+c]+fmvS[g2jS[a*3+1]*4+c]+fmvS[g2jS[a*3+2]*4+c];
            p[c]=v;
          }
          float E=p[0], x_=p[1], y_=p[2], z_=p[3];
          float pt=sqrtf(x_*x_+y_*y_);
          float p3=sqrtf(pt*pt+z_*z_);
          float m =sqrtf(fmaxf(E*E-p3*p3,1e-8f));
          float eta=asinhf(z_/fmaxf(pt,1e-8f));
          float ph=atan2f(y_,x_);
          phys[g*6+0]=m;  phys[g*6+1]=pt; phys[g*6+2]=eta;
          phys[g*6+3]=ph; phys[g*6+4]=E;  phys[g*6+5]=p3;
        }
        float m=0.f; for(int c=0;c<24;c++) m+=phys[c]; m*=(1.0f/24.0f);
        float v=0.f; for(int c=0;c<24;c++){ float t=phys[c]-m; v+=t*t; } v*=(1.0f/24.0f);
        float r=rsqrtf(v+1e-5f);
        for(int c=0;c<24;c++) phys[c]=(phys[c]-m)*r*ldv(phg,c)+ldv(phb,c);
      }
      __syncthreads();
      {
        int k=tid;
        float acc=evt_c[k]+isr_c[isrS[a]*2*ND+k];
        const float* p1=&grpS[g1tS[a]*ND];
        const float* p2=&grpS[g2tS[a]*ND];
        for(int d=0;d<ND;d++){
          float u=p1[d], w=p2[d];
          float dm=u-w;
          acc += (u+w)  *ldv(sW1,(size_t)(  ND+d)*2*ND+k);
          acc += (u*w)  *ldv(sW1,(size_t)(2*ND+d)*2*ND+k);
          acc += (dm*dm)*ldv(sW1,(size_t)(3*ND+d)*2*ND+k);
        }
        for(int c=0;c<24;c++) acc+=phys[c]*ldv(sW1,(size_t)(5*ND+c)*2*ND+k);
        h1[k]=gelu_f(acc);
      }
      __syncthreads();
      if(tid<ND){
        float acc=ldv(sb2,tid);
        for(int f=0;f<2*ND;f++) acc+=h1[f]*ldv(sW2,f*ND+tid);
        h2[tid]=gelu_f(acc);
      }
      __syncthreads();
      if(tid==0){
        float acc=ldv(sb3,0);
        for(int d=0;d<ND;d++) acc+=h2[d]*ldv(sW3,d);
        float outv;
        unsigned bm=badS;
        if(bm)               outv=1000.0f*(float)bm;  // decode: NaN born in phase bit
        else if(bad_f32(acc)) outv=777.0f;            // decode: NaN born in scorer
        else                  outv=acc;
        stv(OUT,(size_t)b*NAS+a,outv);
      }
      __syncthreads();
    }
  }
}

extern "C" void kernel_launch(void* const* d_in, const int* in_sizes, int n_in,
                              void* d_out, int out_size, void* d_ws, size_t ws_size,
                              hipStream_t stream){
  KArgs A;
  for(int i=0;i<54;i++) A.p[i]=d_in[i];
  A.out=d_out;
  A.flag=d_ws;

  // dtype probe on W_in (1024 elements; reads 2KB — safe under either dtype)
  k_detect<<<1,256,0,stream>>>((const unsigned short*)d_in[1],1024,(unsigned*)d_ws);

  // both instantiations launched every call (graph-safe); wrong one exits immediately
  k_all<bf16> <<<NB,256,0,stream>>>(A,0u);
  k_all<float><<<NB,256,0,stream>>>(A,1u);
}

// Round 6
// 11457.364 us; speedup vs baseline: 1.1848x; 1.1848x over previous
//
#include <hip/hip_runtime.h>
#include <hip/hip_bf16.h>
#include <math.h>

typedef __hip_bfloat16 bf16;

constexpr int NB=2048, NJ=7, ND=128, NHD=8, NLYR=4, NFF=512, NTR=35, NAS=70;

struct KArgs { const void* p[54]; void* out; const void* flag; };

__device__ __forceinline__ float bfbits(unsigned short s){ return __uint_as_float(((unsigned)s)<<16); }
__device__ __forceinline__ float ldv(const float* p, size_t i){ return p[i]; }
__device__ __forceinline__ float ldv(const bf16* p, size_t i){ return __bfloat162float(p[i]); }
__device__ __forceinline__ void ldv4(const float* p, size_t i, float* o){
  const float4 v=*reinterpret_cast<const float4*>(p+i);
  o[0]=v.x; o[1]=v.y; o[2]=v.z; o[3]=v.w;
}
__device__ __forceinline__ void ldv4(const bf16* p, size_t i, float* o){
  unsigned long long u=*reinterpret_cast<const unsigned long long*>((const unsigned short*)p+i);
  o[0]=bfbits((unsigned short)u);
  o[1]=bfbits((unsigned short)(u>>16));
  o[2]=bfbits((unsigned short)(u>>32));
  o[3]=bfbits((unsigned short)(u>>48));
}
__device__ __forceinline__ void stv(float* p, size_t i, float v){ p[i]=v; }
__device__ __forceinline__ void stv(bf16* p, size_t i, float v){ p[i]=__float2bfloat16(v); }
__device__ __forceinline__ float gelu_f(float x){ return 0.5f*x*(1.0f+erff(x*0.70710678118654752f)); }

__device__ void build_trips(int* tr){
  int n=0;
  for(int a=0;a<NJ;a++)for(int b=a+1;b<NJ;b++)for(int c=b+1;c<NJ;c++){
    tr[n*3+0]=a; tr[n*3+1]=b; tr[n*3+2]=c; n++;
  }
}
__device__ int find_tid(const int* tr,int a,int b,int c){
  for(int t=0;t<NTR;t++) if(tr[t*3]==a&&tr[t*3+1]==b&&tr[t*3+2]==c) return t;
  return 0;
}
__device__ void build_assign(const int* tr,int* isr,int* g1t,int* g2t,int* g1j,int* g2j){
  int n=0;
  for(int is=0;is<NJ;is++){
    int rem[6],m=0;
    for(int j=0;j<NJ;j++) if(j!=is) rem[m++]=j;
    for(int i=0;i<6;i++)for(int jj=i+1;jj<6;jj++)for(int k=jj+1;k<6;k++){
      int c0=rem[i],c1=rem[jj],c2=rem[k];
      int comp[3],q=0;
      for(int r=0;r<6;r++){ int v=rem[r]; if(v!=c0&&v!=c1&&v!=c2) comp[q++]=v; }
      bool lt=(c0<comp[0])||(c0==comp[0]&&(c1<comp[1]||(c1==comp[1]&&c2<comp[2])));
      if(lt){
        isr[n]=is;
        g1j[n*3]=c0; g1j[n*3+1]=c1; g1j[n*3+2]=c2;
        g2j[n*3]=comp[0]; g2j[n*3+1]=comp[1]; g2j[n*3+2]=comp[2];
        g1t[n]=find_tid(tr,c0,c1,c2);
        g2t[n]=find_tid(tr,comp[0],comp[1],comp[2]);
        n++;
      }
    }
  }
}

// conflict-free LayerNorm over ND=128: 32 lanes/row, shuffle reduce
template<typename T>
__device__ void lnr(const float* src, float* dst, const T* g, const T* bb,
                    float* mu, float* rs, int rows, int tid){
  for(int r0=0;r0<rows;r0+=8){
    int row=r0+(tid>>5), lane=tid&31;
    if(row<rows){
      const float* s=src+row*ND;
      float m=0.f,v=0.f;
      for(int d=lane;d<ND;d+=32){ float t=s[d]; m+=t; v+=t*t; }
      for(int off=16;off>0;off>>=1){ m+=__shfl_down(m,off,32); v+=__shfl_down(v,off,32); }
      if(lane==0){ m*=(1.f/ND); float vv=v*(1.f/ND)-m*m; mu[row]=m; rs[row]=rsqrtf(fmaxf(vv,0.f)+1e-5f); }
    }
    __syncthreads();
  }
  for(int idx=tid; idx<rows*ND; idx+=256){
    int j=idx>>7, d=idx&127;
    dst[idx]=(src[idx]-mu[j])*rs[j]*ldv(g,d)+ldv(bb,d);
  }
  __syncthreads();
}

// out[MxN] = act(a @ W + bias); 4 outputs/thread, vector weight loads. N%4==0.
template<typename T>
__device__ void mm4(const float* a, const T* W, const T* bias, float* out,
                    int M, int K, int N, int tid, int act, bool accum){
  int NQ=N>>2;
  for(int q=tid; q<M*NQ; q+=256){
    int i=q/NQ, k4=(q-i*NQ)<<2;
    float acc[4];
    if(bias) ldv4(bias,k4,acc);
    else { acc[0]=0.f;acc[1]=0.f;acc[2]=0.f;acc[3]=0.f; }
    const float* ar=a+i*K;
    for(int d=0; d<K; d++){
      float w[4]; ldv4(W,(size_t)d*N+k4,w);
      float av=ar[d];
      acc[0]+=av*w[0]; acc[1]+=av*w[1]; acc[2]+=av*w[2]; acc[3]+=av*w[3];
    }
    int o=i*N+k4;
    #pragma unroll
    for(int j=0;j<4;j++){
      float v=acc[j];
      if(act==1) v=fmaxf(v,0.f); else if(act==2) v=gelu_f(v);
      if(accum) out[o+j]+=v; else out[o+j]=v;
    }
  }
  __syncthreads();
}

__global__ void k_detect(const unsigned short* w, int n, unsigned* flag){
  __shared__ int bad[256];
  int tid=threadIdx.x;
  int my=0;
  for(int i=tid;i<n;i+=256){
    unsigned e=(w[i]>>7)&0xFFu;
    if(e>=134u) my=1;
  }
  bad[tid]=my;
  __syncthreads();
  if(tid==0){
    int any=0; for(int i=0;i<256;i++) any|=bad[i];
    flag[0]= any?1u:0u;   // 1 => inputs fp32; 0 => bf16
  }
}

// ---------------- phase device bodies (shared by split & fused) ----------------

template<typename T>
__device__ void phase_embed(const T* fm, const T* Win, const T* bin,
                            const T* ptw, const T* drw, const T* mw,
                            float* xS, float* biasS, float* scratch, int b, int tid){
  float* fE =scratch+0;  float* fpx=scratch+8;  float* fpy=scratch+16; float* fpz=scratch+24;
  float* flp=scratch+32; float* fet=scratch+40; float* fcp=scratch+48; float* fsp=scratch+56;
  float* fph=scratch+64; float* fms=scratch+72;
  if(tid<NJ){
    size_t base=((size_t)b*NJ+tid)*4;
    float e=ldv(fm,base+0), x_=ldv(fm,base+1), y_=ldv(fm,base+2), z_=ldv(fm,base+3);
    float pt=fmaxf(sqrtf(x_*x_+y_*y_),1e-8f);
    fE[tid]=e; fpx[tid]=x_; fpy[tid]=y_; fpz[tid]=z_;
    flp[tid]=logf(pt);
    fet[tid]=asinhf(z_/pt);
    fph[tid]=atan2f(y_,x_);
    fms[tid]=sqrtf(fmaxf(e*e-x_*x_-y_*y_-z_*z_,1e-8f));
    fcp[tid]=x_/pt; fsp[tid]=y_/pt;
  }
  __syncthreads();
  for(int idx=tid; idx<NJ*ND; idx+=256){
    int j=idx>>7, d=idx&127;
    float in8[8]={fE[j],fpx[j],fpy[j],fpz[j],flp[j],fet[j],fph[j],fms[j]};
    float acc=ldv(bin,d);
    for(int c=0;c<8;c++) acc += in8[c]*ldv(Win,c*ND+d);
    xS[idx]=acc;
  }
  for(int idx=tid; idx<NHD*NJ*NJ; idx+=256){
    int h=idx/49, r=idx%49, i=r/7, jj=r%7;
    float ptb=flp[i]-flp[jj];
    float deta=fet[i]-fet[jj];
    float cd=fcp[i]*fcp[jj]+fsp[i]*fsp[jj];
    cd=fminf(fmaxf(cd,-1.0f+1e-7f),1.0f-1e-7f);
    float ac=acosf(cd);
    float dr=sqrtf(deta*deta+ac*ac);
    float Es=fE[i]+fE[jj];
    float sx=fpx[i]+fpx[jj], sy=fpy[i]+fpy[jj], sz=fpz[i]+fpz[jj];
    float mb=0.5f*logf(fmaxf(Es*Es-(sx*sx+sy*sy+sz*sz),1e-8f));
    biasS[idx]=ldv(ptw,h)*ptb+ldv(drw,h)*dr+ldv(mw,h)*mb;
  }
  __syncthreads();
}

template<typename T>
__device__ void phase_enc(float* xS, const float* biasS, float* P, float* muS, float* rsS,
    const T* eWqkv,const T* ebqkv,const T* eWo,const T* ebo,
    const T* eg1,const T* eb1,const T* eg2,const T* eb2,
    const T* eW1,const T* ebb1,const T* eW2,const T* ebb2, int tid){
  float* h  =P+0;
  float* qkv=P+896;
  float* att=P+3584;
  float* sb =P+4480;
  float* ff =P+896;
  for(int l=0;l<NLYR;l++){
    lnr(xS,h,eg1+l*ND,eb1+l*ND,muS,rsS,NJ,tid);
    mm4(h,eWqkv+(size_t)l*ND*3*ND,ebqkv+l*3*ND,qkv,NJ,ND,3*ND,tid,0,false);
    for(int idx=tid;idx<NHD*NJ*NJ;idx+=256){
      int hh=idx/49, r=idx%49, i=r/7, jj=r%7;
      float acc=0.f;
      const float* qr=&qkv[i*384+hh*16];
      const float* kr=&qkv[jj*384+128+hh*16];
      for(int d=0;d<16;d++) acc+=qr[d]*kr[d];
      sb[idx]=acc*0.25f+biasS[idx];
    }
    __syncthreads();
    if(tid<NHD*NJ){
      float* s=&sb[tid*7];
      float mx=s[0]; for(int j=1;j<7;j++) mx=fmaxf(mx,s[j]);
      float sm=0.f; for(int j=0;j<7;j++){ s[j]=expf(s[j]-mx); sm+=s[j]; }
      float inv=1.0f/sm; for(int j=0;j<7;j++) s[j]*=inv;
    }
    __syncthreads();
    for(int idx=tid;idx<NJ*ND;idx+=256){
      int i=idx>>7, d=idx&127, hh=d>>4;
      float acc=0.f;
      for(int j=0;j<7;j++) acc+=sb[(hh*7+i)*7+j]*qkv[j*384+256+d];
      att[idx]=acc;
    }
    __syncthreads();
    mm4(att,eWo+(size_t)l*ND*ND,ebo+l*ND,xS,NJ,ND,ND,tid,0,true);
    lnr(xS,h,eg2+l*ND,eb2+l*ND,muS,rsS,NJ,tid);
    mm4(h,eW1+(size_t)l*ND*NFF,ebb1+l*NFF,ff,NJ,ND,NFF,tid,1,false);
    mm4(ff,eW2+(size_t)l*NFF*ND,ebb2+l*ND,xS,NJ,NFF,ND,tid,0,true);
  }
}

template<typename T>
__device__ void phase_tca(float* xS, float* P, float* muS, float* rsS, const int* trS,
    const T* tWq,const T* tbq,const T* tWk,const T* tbk,const T* tWv,const T* tbv,
    const T* tWo,const T* tbo,const T* tg1,const T* tb1,const T* tW1,const T* tbb1,
    const T* tW2,const T* tbb2,const T* tg2,const T* tb2, int tid){
  float* q   =P+0;     // 896
  float* kv  =P+896;   // 4480
  float* sb4 =P+5376;  // 980
  float* att2=P+6356;  // 896
  float* tff =P+0;     // 1792, after q/kv dead
  const float sc=0.17677669529663687f;
  mm4(xS,tWq,tbq,q,NJ,ND,ND,tid,0,false);
  for(int q2=tid;q2<NTR*32;q2+=256){
    int t=q2>>5, d4=(q2&31)<<2;
    int a0=trS[t*3]*ND, a1=trS[t*3+1]*ND, a2=trS[t*3+2]*ND;
    float acc[4]; ldv4(tbk,d4,acc);
    for(int c=0;c<ND;c++){
      float tv=(xS[a0+c]+xS[a1+c]+xS[a2+c])*(1.0f/3.0f);
      float w[4]; ldv4(tWk,(size_t)c*ND+d4,w);
      acc[0]+=tv*w[0]; acc[1]+=tv*w[1]; acc[2]+=tv*w[2]; acc[3]+=tv*w[3];
    }
    int o=t*ND+d4;
    kv[o]=acc[0]; kv[o+1]=acc[1]; kv[o+2]=acc[2]; kv[o+3]=acc[3];
  }
  __syncthreads();
  for(int idx=tid;idx<4*NJ*NTR;idx+=256){
    int hh=idx/245, r=idx%245, i=r/35, t=r%35;
    float acc=0.f;
    const float* qr=&q[i*ND+hh*32];
    const float* kr=&kv[t*ND+hh*32];
    for(int d=0;d<32;d++) acc+=qr[d]*kr[d];
    bool mem=(trS[t*3]==i||trS[t*3+1]==i||trS[t*3+2]==i);
    sb4[idx]=acc*sc+(mem?0.0f:-1e9f);
  }
  __syncthreads();
  if(tid<4*NJ){
    float* s=&sb4[tid*35];
    float mx=-3e38f; for(int t=0;t<35;t++) mx=fmaxf(mx,s[t]);
    float sm=0.f; for(int t=0;t<35;t++){ s[t]=expf(s[t]-mx); sm+=s[t]; }
    float inv=1.0f/sm; for(int t=0;t<35;t++) s[t]*=inv;
  }
  __syncthreads();
  for(int q2=tid;q2<NTR*32;q2+=256){
    int t=q2>>5, d4=(q2&31)<<2;
    int a0=trS[t*3]*ND, a1=trS[t*3+1]*ND, a2=trS[t*3+2]*ND;
    float acc[4]; ldv4(tbv,d4,acc);
    for(int c=0;c<ND;c++){
      float tv=(xS[a0+c]+xS[a1+c]+xS[a2+c])*(1.0f/3.0f);
      float w[4]; ldv4(tWv,(size_t)c*ND+d4,w);
      acc[0]+=tv*w[0]; acc[1]+=tv*w[1]; acc[2]+=tv*w[2]; acc[3]+=tv*w[3];
    }
    int o=t*ND+d4;
    kv[o]=acc[0]; kv[o+1]=acc[1]; kv[o+2]=acc[2]; kv[o+3]=acc[3];
  }
  __syncthreads();
  for(int idx=tid;idx<NJ*ND;idx+=256){
    int i=idx>>7, d=idx&127, hh=d>>5;
    float acc=0.f;
    for(int t=0;t<35;t++) acc+=sb4[(hh*7+i)*35+t]*kv[t*ND+d];
    att2[idx]=acc;
  }
  __syncthreads();
  mm4(att2,tWo,tbo,xS,NJ,ND,ND,tid,0,true);
  lnr(xS,xS,tg1,tb1,muS,rsS,NJ,tid);
  mm4(xS,tW1,tbb1,tff,NJ,ND,2*ND,tid,2,false);
  mm4(tff,tW2,tbb2,xS,NJ,2*ND,ND,tid,0,true);
  lnr(xS,xS,tg2,tb2,muS,rsS,NJ,tid);
}

// group transformer chunk: tokens of triplets [c0, c0+tc) from jets[7*ND] -> grp rows
template<typename T>
__device__ void phase_gt_chunk(const float* jets, float* grp_out, int c0, int tc,
    float* xg, float* hg, float* qkvg, float* attg, float* sbg,
    float* muS, float* rsS, const int* trS,
    const T* gWqkv,const T* gbqkv,const T* gWo,const T* gbo,
    const T* gg1,const T* gb1,const T* gg2,const T* gb2,
    const T* gW1,const T* gbb1,const T* gW2,const T* gbb2, int tid){
  int ntok=3*tc;
  const float sc=0.17677669529663687f;
  for(int idx=tid;idx<ntok*ND;idx+=256){
    int s=idx>>7, d=idx&127; int t=c0+s/3, r=s%3;
    xg[idx]=jets[trS[t*3+r]*ND+d];
  }
  __syncthreads();
  lnr(xg,hg,gg1,gb1,muS,rsS,ntok,tid);
  mm4(hg,gWqkv,gbqkv,qkvg,ntok,ND,3*ND,tid,0,false);
  for(int idx=tid;idx<tc*36;idx+=256){
    int s=idx/36, r=idx%36, hh=r/9, p=r%9, i=p/3, j=p%3;
    float acc=0.f;
    const float* qr=&qkvg[(s*3+i)*384+hh*32];
    const float* kr=&qkvg[(s*3+j)*384+128+hh*32];
    for(int d=0;d<32;d++) acc+=qr[d]*kr[d];
    sbg[idx]=acc*sc;
  }
  __syncthreads();
  for(int q2=tid;q2<tc*12;q2+=256){
    int s=q2/12, r2=q2%12;
    float* base=&sbg[s*36+(r2/3)*9+(r2%3)*3];
    float mx=fmaxf(base[0],fmaxf(base[1],base[2]));
    float e0=expf(base[0]-mx),e1=expf(base[1]-mx),e2=expf(base[2]-mx);
    float inv=1.0f/(e0+e1+e2);
    base[0]=e0*inv; base[1]=e1*inv; base[2]=e2*inv;
  }
  __syncthreads();
  for(int idx=tid;idx<ntok*ND;idx+=256){
    int sr=idx>>7, d=idx&127; int s=sr/3, i=sr%3, hh=d>>5;
    float acc=0.f;
    for(int j=0;j<3;j++) acc+=sbg[s*36+hh*9+i*3+j]*qkvg[(s*3+j)*384+256+d];
    attg[idx]=acc;
  }
  __syncthreads();
  mm4(attg,gWo,gbo,xg,ntok,ND,ND,tid,0,true);
  lnr(xg,hg,gg2,gb2,muS,rsS,ntok,tid);
  mm4(hg,gW1,gbb1,qkvg,ntok,ND,2*ND,tid,1,false);   // ffg aliases qkvg
  mm4(qkvg,gW2,gbb2,xg,ntok,2*ND,ND,tid,0,true);
  for(int idx=tid;idx<tc*ND;idx+=256){
    int s=idx>>7, d=idx&127;
    grp_out[s*ND+d]=(xg[(s*3)*ND+d]+xg[(s*3+1)*ND+d]+xg[(s*3+2)*ND+d])*(1.0f/3.0f);
  }
  __syncthreads();
}

// scorer: grpS[NTR*ND], jets[NJ*ND] (in U), evtS, fmvS in LDS. U layout:
//   U[0..895]=jets (dead after isr_c); then h1=U+0(256), h2=U+256(128), physAll=U+384(1680)
template<typename T>
__device__ void phase_score(const float* grpS, float* U, const float* evtS, const float* fmvS,
    float* isr_c, float* evt_c,
    const int* isrS, const int* g1tS, const int* g2tS, const int* g1jS, const int* g2jS,
    const T* phg, const T* phb,
    const T* sW1,const T* sb1,const T* sW2,const T* sb2,const T* sW3,const T* sb3,
    T* OUT, int b, int tid){
  float* jets=U;
  float* h1=U;          // after jets dead
  float* h2=U+256;
  float* physAll=U+384; // 70*24
  mm4(evtS,sW1+(size_t)4*ND*2*ND,sb1,evt_c,1,ND,2*ND,tid,0,false);
  mm4(jets,sW1,(const T*)nullptr,isr_c,NJ,ND,2*ND,tid,0,false);
  // jets now dead; compute physics features for all assignments
  for(int t=tid;t<NAS*4;t+=256){
    int a=t>>2, g=t&3;
    float p[4];
    #pragma unroll
    for(int c=0;c<4;c++){
      float v;
      if(g==0)      v=fmvS[g1jS[a*3]*4+c]+fmvS[g1jS[a*3+1]*4+c]+fmvS[g1jS[a*3+2]*4+c];
      else if(g==1) v=fmvS[g2jS[a*3]*4+c]+fmvS[g2jS[a*3+1]*4+c]+fmvS[g2jS[a*3+2]*4+c];
      else if(g==2) v=fmvS[isrS[a]*4+c];
      else          v=fmvS[g1jS[a*3]*4+c]+fmvS[g1jS[a*3+1]*4+c]+fmvS[g1jS[a*3+2]*4+c]
                     +fmvS[g2jS[a*3]*4+c]+fmvS[g2jS[a*3+1]*4+c]+fmvS[g2jS[a*3+2]*4+c];
      p[c]=v;
    }
    float E=p[0], x_=p[1], y_=p[2], z_=p[3];
    float pt=sqrtf(x_*x_+y_*y_);
    float p3=sqrtf(pt*pt+z_*z_);
    float m =sqrtf(fmaxf(E*E-p3*p3,1e-8f));
    float eta=asinhf(z_/fmaxf(pt,1e-8f));
    float ph=atan2f(y_,x_);
    float* o=&physAll[a*24+g*6];
    o[0]=m; o[1]=pt; o[2]=eta; o[3]=ph; o[4]=E; o[5]=p3;
  }
  __syncthreads();
  for(int a=tid;a<NAS;a+=256){
    float* o=&physAll[a*24];
    float m=0.f; for(int c=0;c<24;c++) m+=o[c]; m*=(1.0f/24.0f);
    float v=0.f; for(int c=0;c<24;c++){ float t=o[c]-m; v+=t*t; } v*=(1.0f/24.0f);
    float r=rsqrtf(v+1e-5f);
    for(int c=0;c<24;c++) o[c]=(o[c]-m)*r*ldv(phg,c)+ldv(phb,c);
  }
  __syncthreads();
  for(int a=0;a<NAS;a++){
    {
      int k=tid;
      float acc=evt_c[k]+isr_c[isrS[a]*2*ND+k];
      const float* p1=&grpS[g1tS[a]*ND];
      const float* p2=&grpS[g2tS[a]*ND];
      for(int d=0;d<ND;d++){
        float u=p1[d], w=p2[d];
        float dm=u-w;
        acc += (u+w)  *ldv(sW1,(size_t)(  ND+d)*2*ND+k);
        acc += (u*w)  *ldv(sW1,(size_t)(2*ND+d)*2*ND+k);
        acc += (dm*dm)*ldv(sW1,(size_t)(3*ND+d)*2*ND+k);
      }
      const float* ph=&physAll[a*24];
      for(int c=0;c<24;c++) acc+=ph[c]*ldv(sW1,(size_t)(5*ND+c)*2*ND+k);
      h1[k]=gelu_f(acc);
    }
    __syncthreads();
    if(tid<ND){
      float acc=ldv(sb2,tid);
      for(int f=0;f<2*ND;f++) acc+=h1[f]*ldv(sW2,f*ND+tid);
      h2[tid]=gelu_f(acc);
    }
    __syncthreads();
    if(tid<64){
      float part=h2[tid]*ldv(sW3,tid)+h2[tid+64]*ldv(sW3,tid+64);
      for(int off=32;off>0;off>>=1) part+=__shfl_down(part,off,64);
      if(tid==0) stv(OUT,(size_t)b*NAS+a,part+ldv(sb3,0));
    }
    __syncthreads();
  }
}

// ---------------- split-path kernels ----------------

template<typename T>
__global__ __launch_bounds__(256) void k_front(KArgs A, unsigned want, float* X2, float* EVT){
  if(((const unsigned*)A.flag)[0]!=want) return;
  int b=blockIdx.x, tid=threadIdx.x;
  __shared__ float xS[NJ*ND];
  __shared__ float biasS[NHD*NJ*NJ];
  __shared__ float P[7400];
  __shared__ float muS[16], rsS[16];
  __shared__ int trS[NTR*3];
  if(tid==0) build_trips(trS);
  __syncthreads();
  phase_embed((const T*)A.p[0],(const T*)A.p[1],(const T*)A.p[2],
              (const T*)A.p[3],(const T*)A.p[4],(const T*)A.p[5],xS,biasS,P,b,tid);
  phase_enc(xS,biasS,P,muS,rsS,
    (const T*)A.p[6],(const T*)A.p[7],(const T*)A.p[8],(const T*)A.p[9],
    (const T*)A.p[10],(const T*)A.p[11],(const T*)A.p[12],(const T*)A.p[13],
    (const T*)A.p[14],(const T*)A.p[15],(const T*)A.p[16],(const T*)A.p[17],tid);
  phase_tca(xS,P,muS,rsS,trS,
    (const T*)A.p[18],(const T*)A.p[19],(const T*)A.p[20],(const T*)A.p[21],
    (const T*)A.p[22],(const T*)A.p[23],(const T*)A.p[24],(const T*)A.p[25],
    (const T*)A.p[26],(const T*)A.p[27],(const T*)A.p[28],(const T*)A.p[29],
    (const T*)A.p[30],(const T*)A.p[31],(const T*)A.p[32],(const T*)A.p[33],tid);
  for(int idx=tid;idx<NJ*ND;idx+=256) X2[(size_t)b*NJ*ND+idx]=xS[idx];
  if(tid<ND){
    float s=0.f; for(int j=0;j<NJ;j++) s+=xS[j*ND+tid];
    EVT[(size_t)b*ND+tid]=s*(1.0f/NJ);
  }
}

template<typename T>
__global__ __launch_bounds__(256) void k_gt(KArgs A, unsigned want, const float* X2, float* GRP){
  if(((const unsigned*)A.flag)[0]!=want) return;
  int b=blockIdx.x/12, ch=blockIdx.x%12, tid=threadIdx.x;
  int c0=ch*3, tc=(NTR-c0)<3?(NTR-c0):3;
  __shared__ float jets[NJ*ND];
  __shared__ float xg[1152],hg[1152],qkvg[3456],attg[1152],sbg[108];
  __shared__ float muS[16], rsS[16];
  __shared__ float grp_loc[3*ND];
  __shared__ int trS[NTR*3];
  if(tid==0) build_trips(trS);
  for(int idx=tid;idx<NJ*ND;idx+=256) jets[idx]=X2[(size_t)b*NJ*ND+idx];
  __syncthreads();
  phase_gt_chunk(jets,grp_loc,c0,tc,xg,hg,qkvg,attg,sbg,muS,rsS,trS,
    (const T*)A.p[34],(const T*)A.p[35],(const T*)A.p[36],(const T*)A.p[37],
    (const T*)A.p[38],(const T*)A.p[39],(const T*)A.p[40],(const T*)A.p[41],
    (const T*)A.p[42],(const T*)A.p[43],(const T*)A.p[44],(const T*)A.p[45],tid);
  for(int idx=tid;idx<tc*ND;idx+=256)
    GRP[((size_t)b*NTR+c0)*ND+idx]=grp_loc[idx];
}

template<typename T>
__global__ __launch_bounds__(256) void k_score(KArgs A, unsigned want,
    const float* X2, const float* EVT, const float* GRP){
  if(((const unsigned*)A.flag)[0]!=want) return;
  int b=blockIdx.x, tid=threadIdx.x;
  __shared__ float grpS[NTR*ND];
  __shared__ float U[2064];
  __shared__ float evtS[ND];
  __shared__ float fmvS[NJ*4];
  __shared__ float isr_c[NJ*2*ND];
  __shared__ float evt_c[2*ND];
  __shared__ int trS[NTR*3];
  __shared__ int isrS[NAS], g1tS[NAS], g2tS[NAS], g1jS[NAS*3], g2jS[NAS*3];
  if(tid==0){ build_trips(trS); build_assign(trS,isrS,g1tS,g2tS,g1jS,g2jS); }
  for(int idx=tid;idx<NTR*ND;idx+=256) grpS[idx]=GRP[(size_t)b*NTR*ND+idx];
  for(int idx=tid;idx<NJ*ND;idx+=256) U[idx]=X2[(size_t)b*NJ*ND+idx];
  if(tid<ND) evtS[tid]=EVT[(size_t)b*ND+tid];
  if(tid>=128&&tid<128+NJ*4){ int q=tid-128; fmvS[q]=ldv((const T*)A.p[0],(size_t)b*NJ*4+q); }
  __syncthreads();
  phase_score(grpS,U,evtS,fmvS,isr_c,evt_c,isrS,g1tS,g2tS,g1jS,g2jS,
    (const T*)A.p[46],(const T*)A.p[47],
    (const T*)A.p[48],(const T*)A.p[49],(const T*)A.p[50],(const T*)A.p[51],
    (const T*)A.p[52],(const T*)A.p[53],(T*)A.out,b,tid);
}

// ---------------- fused fallback (no workspace needed) ----------------

template<typename T>
__global__ __launch_bounds__(256) void k_fused(KArgs A, unsigned want){
  if(((const unsigned*)A.flag)[0]!=want) return;
  int b=blockIdx.x, tid=threadIdx.x;
  __shared__ float xS[NJ*ND];
  __shared__ float biasS[NHD*NJ*NJ];
  __shared__ float evtS[ND];
  __shared__ float fmvS[NJ*4];
  __shared__ float grpS[NTR*ND];
  __shared__ float muS[16], rsS[16];
  __shared__ float P[7400];
  __shared__ int trS[NTR*3];
  __shared__ int isrS[NAS], g1tS[NAS], g2tS[NAS], g1jS[NAS*3], g2jS[NAS*3];
  if(tid==0){ build_trips(trS); build_assign(trS,isrS,g1tS,g2tS,g1jS,g2jS); }
  __syncthreads();
  if(tid>=128&&tid<128+NJ*4){ int q=tid-128; fmvS[q]=ldv((const T*)A.p[0],(size_t)b*NJ*4+q); }
  phase_embed((const T*)A.p[0],(const T*)A.p[1],(const T*)A.p[2],
              (const T*)A.p[3],(const T*)A.p[4],(const T*)A.p[5],xS,biasS,P,b,tid);
  phase_enc(xS,biasS,P,muS,rsS,
    (const T*)A.p[6],(const T*)A.p[7],(const T*)A.p[8],(const T*)A.p[9],
    (const T*)A.p[10],(const T*)A.p[11],(const T*)A.p[12],(const T*)A.p[13],
    (const T*)A.p[14],(const T*)A.p[15],(const T*)A.p[16],(const T*)A.p[17],tid);
  phase_tca(xS,P,muS,rsS,trS,
    (const T*)A.p[18],(const T*)A.p[19],(const T*)A.p[20],(const T*)A.p[21],
    (const T*)A.p[22],(const T*)A.p[23],(const T*)A.p[24],(const T*)A.p[25],
    (const T*)A.p[26],(const T*)A.p[27],(const T*)A.p[28],(const T*)A.p[29],
    (const T*)A.p[30],(const T*)A.p[31],(const T*)A.p[32],(const T*)A.p[33],tid);
  if(tid<ND){
    float s=0.f; for(int j=0;j<NJ;j++) s+=xS[j*ND+tid];
    evtS[tid]=s*(1.0f/NJ);
  }
  __syncthreads();
  // group transformer into grpS using P as scratch
  {
    float* xg  =P+0;
    float* hg  =P+1152;
    float* qkvg=P+2304;
    float* attg=P+5760;
    float* sbg =P+6912;
    for(int c0=0;c0<NTR;c0+=3){
      int tc=(NTR-c0)<3?(NTR-c0):3;
      phase_gt_chunk(xS,grpS+c0*ND,c0,tc,xg,hg,qkvg,attg,sbg,muS,rsS,trS,
        (const T*)A.p[34],(const T*)A.p[35],(const T*)A.p[36],(const T*)A.p[37],
        (const T*)A.p[38],(const T*)A.p[39],(const T*)A.p[40],(const T*)A.p[41],
        (const T*)A.p[42],(const T*)A.p[43],(const T*)A.p[44],(const T*)A.p[45],tid);
    }
  }
  // scorer: U region inside P; jets already in xS — copy to U
  {
    float* U    =P+0;     // 2064
    float* isr_c=P+2064;  // 1792
    float* evt_c=P+3856;  // 256
    for(int idx=tid;idx<NJ*ND;idx+=256) U[idx]=xS[idx];
    __syncthreads();
    phase_score(grpS,U,evtS,fmvS,isr_c,evt_c,isrS,g1tS,g2tS,g1jS,g2jS,
      (const T*)A.p[46],(const T*)A.p[47],
      (const T*)A.p[48],(const T*)A.p[49],(const T*)A.p[50],(const T*)A.p[51],
      (const T*)A.p[52],(const T*)A.p[53],(T*)A.out,b,tid);
  }
}

extern "C" void kernel_launch(void* const* d_in, const int* in_sizes, int n_in,
                              void* d_out, int out_size, void* d_ws, size_t ws_size,
                              hipStream_t stream){
  KArgs A;
  for(int i=0;i<54;i++) A.p[i]=d_in[i];
  A.out=d_out;
  A.flag=d_ws;

  float* ws=(float*)d_ws;
  float* X2 = ws+16;
  float* EVT = X2 + (size_t)NB*NJ*ND;
  float* GRP = EVT + (size_t)NB*ND;
  size_t need = (16 + (size_t)NB*NJ*ND + (size_t)NB*ND + (size_t)NB*NTR*ND)*sizeof(float);

  k_detect<<<1,256,0,stream>>>((const unsigned short*)d_in[1],1024,(unsigned*)d_ws);

  if(ws_size>=need){
    k_front<bf16> <<<NB,256,0,stream>>>(A,0u,X2,EVT);
    k_front<float><<<NB,256,0,stream>>>(A,1u,X2,EVT);
    k_gt<bf16>    <<<NB*12,256,0,stream>>>(A,0u,X2,GRP);
    k_gt<float>   <<<NB*12,256,0,stream>>>(A,1u,X2,GRP);
    k_score<bf16> <<<NB,256,0,stream>>>(A,0u,X2,EVT,GRP);
    k_score<float><<<NB,256,0,stream>>>(A,1u,X2,EVT,GRP);
  } else {
    k_fused<bf16> <<<NB,256,0,stream>>>(A,0u);
    k_fused<float><<<NB,256,0,stream>>>(A,1u);
  }
}